// Round 2
// baseline (8825.669 us; speedup 1.0000x reference)
//
#include <hip/hip_runtime.h>
#include <hip/hip_bf16.h>
#include <hip/hip_cooperative_groups.h>

namespace cg = cooperative_groups;

#define HD   1024
#define G4   4096
#define CND  64
#define LAT  256
#define VOC  32000
#define TT   256
#define ZCN  320   // LAT + CND

__device__ __forceinline__ float sigf(float x) { return 1.0f / (1.0f + expf(-x)); }

// ---------------------------------------------------------------------------
// k_pre: pre[t][n] = dot(emb[ids[t]], wih[n]) + bih[n] + bhh[n]
// M=256 (t), N=4096 (gate rows), K=1024.  64x64 tiles, BK=32, 256 threads.
// grid = 4*64 = 256 blocks.
// ---------------------------------------------------------------------------
__global__ __launch_bounds__(256) void k_pre(
    const float* __restrict__ emb, const int* __restrict__ ids,
    const float* __restrict__ wih, const float* __restrict__ bih,
    const float* __restrict__ bhh, float* __restrict__ pre, int shift)
{
    __shared__ float As[64 * 36];
    __shared__ float Bs[64 * 36];
    __shared__ int ids_s[64];

    const int bid = blockIdx.x;
    const int m0 = (bid >> 6) * 64;
    const int n0 = (bid & 63) * 64;
    const int tid = threadIdx.x;

    if (tid < 64) {
        int t = m0 + tid;
        ids_s[tid] = shift ? ((t == 0) ? 0 : ids[t - 1]) : ids[t];
    }
    __syncthreads();

    const int r  = tid >> 2;          // 0..63 staging row
    const int c0 = (tid & 3) * 8;     // 0/8/16/24 staging col
    const int ty = tid >> 4, tx = tid & 15;

    float acc[4][4] = {};

    for (int k0 = 0; k0 < HD; k0 += 32) {
        __syncthreads();
        {
            const float4* pa = (const float4*)(emb + (size_t)ids_s[r] * HD + k0 + c0);
            float4 a0 = pa[0], a1 = pa[1];
            float* d = &As[r * 36 + c0];
            d[0] = a0.x; d[1] = a0.y; d[2] = a0.z; d[3] = a0.w;
            d[4] = a1.x; d[5] = a1.y; d[6] = a1.z; d[7] = a1.w;
            const float4* pb = (const float4*)(wih + (size_t)(n0 + r) * HD + k0 + c0);
            float4 b0 = pb[0], b1 = pb[1];
            float* e = &Bs[r * 36 + c0];
            e[0] = b0.x; e[1] = b0.y; e[2] = b0.z; e[3] = b0.w;
            e[4] = b1.x; e[5] = b1.y; e[6] = b1.z; e[7] = b1.w;
        }
        __syncthreads();
        #pragma unroll
        for (int kk = 0; kk < 32; ++kk) {
            float a[4], b[4];
            #pragma unroll
            for (int i = 0; i < 4; ++i) a[i] = As[(ty * 4 + i) * 36 + kk];
            #pragma unroll
            for (int j = 0; j < 4; ++j) b[j] = Bs[(tx * 4 + j) * 36 + kk];
            #pragma unroll
            for (int i = 0; i < 4; ++i)
                #pragma unroll
                for (int j = 0; j < 4; ++j)
                    acc[i][j] = fmaf(a[i], b[j], acc[i][j]);
        }
    }

    #pragma unroll
    for (int j = 0; j < 4; ++j) {
        int n = n0 + tx * 4 + j;
        float bias = bih[n] + bhh[n];
        #pragma unroll
        for (int i = 0; i < 4; ++i) {
            int m = m0 + ty * 4 + i;
            pre[(size_t)m * G4 + n] = acc[i][j] + bias;
        }
    }
}

// ---------------------------------------------------------------------------
// k_out: logits[t][n] = dot(hs[t], out_w[n]) + out_b[n]   (fp32 out)
// M=256, N=32000, K=1024. 64x64 tiles -> grid = 4*500 = 2000 blocks.
// ---------------------------------------------------------------------------
__global__ __launch_bounds__(256) void k_out(
    const float* __restrict__ hs, const float* __restrict__ ow,
    const float* __restrict__ ob, float* __restrict__ outp)
{
    __shared__ float As[64 * 36];
    __shared__ float Bs[64 * 36];

    const int bid = blockIdx.x;
    const int m0 = (bid / 500) * 64;
    const int n0 = (bid % 500) * 64;
    const int tid = threadIdx.x;

    const int r  = tid >> 2;
    const int c0 = (tid & 3) * 8;
    const int ty = tid >> 4, tx = tid & 15;

    float acc[4][4] = {};

    for (int k0 = 0; k0 < HD; k0 += 32) {
        __syncthreads();
        {
            const float4* pa = (const float4*)(hs + (size_t)(m0 + r) * HD + k0 + c0);
            float4 a0 = pa[0], a1 = pa[1];
            float* d = &As[r * 36 + c0];
            d[0] = a0.x; d[1] = a0.y; d[2] = a0.z; d[3] = a0.w;
            d[4] = a1.x; d[5] = a1.y; d[6] = a1.z; d[7] = a1.w;
            const float4* pb = (const float4*)(ow + (size_t)(n0 + r) * HD + k0 + c0);
            float4 b0 = pb[0], b1 = pb[1];
            float* e = &Bs[r * 36 + c0];
            e[0] = b0.x; e[1] = b0.y; e[2] = b0.z; e[3] = b0.w;
            e[4] = b1.x; e[5] = b1.y; e[6] = b1.z; e[7] = b1.w;
        }
        __syncthreads();
        #pragma unroll
        for (int kk = 0; kk < 32; ++kk) {
            float a[4], b[4];
            #pragma unroll
            for (int i = 0; i < 4; ++i) a[i] = As[(ty * 4 + i) * 36 + kk];
            #pragma unroll
            for (int j = 0; j < 4; ++j) b[j] = Bs[(tx * 4 + j) * 36 + kk];
            #pragma unroll
            for (int i = 0; i < 4; ++i)
                #pragma unroll
                for (int j = 0; j < 4; ++j)
                    acc[i][j] = fmaf(a[i], b[j], acc[i][j]);
        }
    }

    #pragma unroll
    for (int j = 0; j < 4; ++j) {
        int n = n0 + tx * 4 + j;
        float bias = ob[n];
        #pragma unroll
        for (int i = 0; i < 4; ++i) {
            int m = m0 + ty * 4 + i;
            outp[(size_t)m * VOC + n] = acc[i][j] + bias;
        }
    }
}

// ---------------------------------------------------------------------------
// k_seq: cooperative. 128 WGs x 256 threads. WG w owns h-rows [w*8, w*8+8).
// Thread layout: rl = tid>>3 in 0..31 -> gate = rl>>3, jl = rl&7,
// row = gate*1024 + w*8 + jl; s = tid&7 = k-slice (128 consecutive k each).
// 128 fp32 whh weights live in VGPRs per thread (float4 wreg[32]).
// Per step: stage h (4KB, bank-conflict-padded) to LDS, 128 FMA (4 accs),
// 8-lane shuffle reduce, gate math on 8 threads, grid.sync().
// ---------------------------------------------------------------------------
__device__ __forceinline__ void load_w(float4 (&wreg)[32], const float* w,
                                       int row, int s)
{
    const float4* p = (const float4*)(w + (size_t)row * HD + s * 128);
    #pragma unroll
    for (int u = 0; u < 32; ++u) wreg[u] = p[u];
}

__device__ __forceinline__ void lstm_loop(cg::grid_group& grid,
    const float4 (&wreg)[32], const float* __restrict__ pre,
    float* __restrict__ h_buf, float* __restrict__ hs, float& c_reg,
    float* h_lds, float* g_lds, int tid, int s, int rl, int row, int j_own)
{
    for (int t = 0; t < TT; ++t) {
        grid.sync();
        // stage h[t] into LDS, padded: chunk c (128 floats) at float offset c*132
        const float4* hb4 = (const float4*)(h_buf + (t & 1) * HD);
        ((float4*)h_lds)[(tid >> 5) * 33 + (tid & 31)] = hb4[tid];
        __syncthreads();
        const float4* h4 = (const float4*)h_lds;
        float a0 = 0.f, a1 = 0.f, a2 = 0.f, a3 = 0.f;
        #pragma unroll
        for (int u = 0; u < 32; ++u) {
            float4 wv = wreg[u];
            float4 hv = h4[s * 33 + u];
            a0 = fmaf(wv.x, hv.x, a0);
            a1 = fmaf(wv.y, hv.y, a1);
            a2 = fmaf(wv.z, hv.z, a2);
            a3 = fmaf(wv.w, hv.w, a3);
        }
        float acc = (a0 + a1) + (a2 + a3);
        acc += __shfl_xor(acc, 1);
        acc += __shfl_xor(acc, 2);
        acc += __shfl_xor(acc, 4);
        if (s == 0) g_lds[rl] = acc + pre[(size_t)t * G4 + row];
        __syncthreads();
        if (tid < 8) {
            float xi = g_lds[tid],      xf = g_lds[8 + tid];
            float xg = g_lds[16 + tid], xo = g_lds[24 + tid];
            c_reg = sigf(xf) * c_reg + sigf(xi) * tanhf(xg);
            float hv = sigf(xo) * tanhf(c_reg);
            h_buf[((t + 1) & 1) * HD + j_own] = hv;
            if (hs) hs[(size_t)t * HD + j_own] = hv;
        }
    }
}

__global__ __launch_bounds__(256, 1) void k_seq(
    const float* __restrict__ cond_emb, const float* __restrict__ enc_whh,
    const float* __restrict__ mean_w, const float* __restrict__ mean_b,
    const float* __restrict__ lgv_w, const float* __restrict__ lgv_b,
    const float* __restrict__ l2h_w, const float* __restrict__ l2h_b,
    const float* __restrict__ l2c_w, const float* __restrict__ l2c_b,
    const float* __restrict__ dec_whh, const float* __restrict__ eps,
    const int* __restrict__ p_ic, const int* __restrict__ p_tc,
    const float* __restrict__ pre_enc, const float* __restrict__ pre_dec,
    float* __restrict__ h_buf, float* __restrict__ z_buf,
    float* __restrict__ hs, float* __restrict__ out_mlgv)
{
    cg::grid_group grid = cg::this_grid();
    __shared__ float h_lds[8 * 132];   // 1056 floats (padded h staging)
    __shared__ float g_lds[32];
    __shared__ float red[16];
    __shared__ float sm[4];

    const int w   = blockIdx.x;        // 0..127
    const int tid = threadIdx.x;
    const int s   = tid & 7;           // k-slice
    const int rl  = tid >> 3;          // 0..31
    const int gate = rl >> 3;
    const int jl   = rl & 7;
    const int row  = gate * HD + w * 8 + jl;
    const int j_own = w * 8 + tid;     // valid for tid<8
    float c_reg = 0.f;

    // ---- encoder initial hidden: zeros(H-C) ++ cond_emb[input_c] ----
    if (tid < 8) {
        int j = w * 8 + tid;
        float v = 0.f;
        int ic = p_ic[0];
        if (j >= HD - CND) v = cond_emb[ic * CND + (j - (HD - CND))];
        h_buf[j] = v;   // buffer 0
    }

    float4 wreg[32];
    load_w(wreg, enc_whh, row, s);
    lstm_loop(grid, wreg, pre_enc, h_buf, nullptr, c_reg,
              h_lds, g_lds, tid, s, rl, row, j_own);

    grid.sync();                       // hT in h_buf buffer 0

    // ---- latent 1: m, lgv, z.  4 wave-groups of 64 lanes, 2 rows each kind ----
    ((float4*)h_lds)[tid] = ((const float4*)h_buf)[tid];  // linear, 1024 floats
    __syncthreads();
    {
        int d = tid >> 6;              // 0..3
        int l64 = tid & 63;
        int l = w * 2 + (d & 1);
        const float* wrow = (d < 2 ? mean_w : lgv_w) + (size_t)l * HD;
        float acc = 0.f;
        #pragma unroll
        for (int e = 0; e < 16; ++e) {
            int k = e * 64 + l64;
            acc = fmaf(wrow[k], h_lds[k], acc);
        }
        #pragma unroll
        for (int o = 32; o >= 1; o >>= 1) acc += __shfl_xor(acc, o);
        if (l64 == 0) sm[d] = acc + (d < 2 ? mean_b : lgv_b)[l];
    }
    __syncthreads();
    if (tid < 2) {
        int l = w * 2 + tid;
        float m = sm[tid], lg = sm[2 + tid];
        float z = eps[l] * expf(0.5f * lg) + m;
        z_buf[l] = z;
        out_mlgv[l]       = m;
        out_mlgv[LAT + l] = lg;
    }
    grid.sync();                       // z_buf visible everywhere

    // ---- latent 2: zc = [z, cond_emb[target_c]]; dh0 -> h_buf[0], dc0 -> c ----
    {
        int tc = p_tc[0];
        for (int idx = tid; idx < ZCN; idx += 256)
            h_lds[idx] = (idx < LAT) ? z_buf[idx]
                                     : cond_emb[tc * CND + idx - LAT];
    }
    __syncthreads();
    {
        int r2 = tid >> 4;             // 0..15 (8 dh rows + 8 dc rows)
        int l16 = tid & 15;
        int which = r2 >> 3;           // 0: l2h, 1: l2c
        int i = w * 8 + (r2 & 7);
        const float* wrow = (which ? l2c_w : l2h_w) + (size_t)i * ZCN;
        float acc = 0.f;
        #pragma unroll
        for (int e = 0; e < 20; ++e) {
            int k = e * 16 + l16;
            acc = fmaf(wrow[k], h_lds[k], acc);
        }
        acc += __shfl_xor(acc, 1);
        acc += __shfl_xor(acc, 2);
        acc += __shfl_xor(acc, 4);
        acc += __shfl_xor(acc, 8);
        if (l16 == 0) red[r2] = acc + (which ? l2c_b : l2h_b)[i];
    }
    __syncthreads();
    if (tid < 8) {
        h_buf[j_own] = red[tid];       // dh0 into buffer 0
        c_reg = red[8 + tid];          // dc0
    }

    load_w(wreg, dec_whh, row, s);
    lstm_loop(grid, wreg, pre_dec, h_buf, hs, c_reg,
              h_lds, g_lds, tid, s, rl, row, j_own);
}

// ---------------------------------------------------------------------------
extern "C" void kernel_launch(void* const* d_in, const int* in_sizes, int n_in,
                              void* d_out, int out_size, void* d_ws, size_t ws_size,
                              hipStream_t stream)
{
    const float* cond_emb = (const float*)d_in[0];
    const float* enc_emb  = (const float*)d_in[1];
    const float* enc_wih  = (const float*)d_in[2];
    const float* enc_whh  = (const float*)d_in[3];
    const float* enc_bih  = (const float*)d_in[4];
    const float* enc_bhh  = (const float*)d_in[5];
    const float* mean_w   = (const float*)d_in[6];
    const float* mean_b   = (const float*)d_in[7];
    const float* lgv_w    = (const float*)d_in[8];
    const float* lgv_b    = (const float*)d_in[9];
    const float* l2h_w    = (const float*)d_in[10];
    const float* l2h_b    = (const float*)d_in[11];
    const float* l2c_w    = (const float*)d_in[12];
    const float* l2c_b    = (const float*)d_in[13];
    const float* dec_emb  = (const float*)d_in[14];
    const float* dec_wih  = (const float*)d_in[15];
    const float* dec_whh  = (const float*)d_in[16];
    const float* dec_bih  = (const float*)d_in[17];
    const float* dec_bhh  = (const float*)d_in[18];
    const float* out_w    = (const float*)d_in[19];
    const float* out_b    = (const float*)d_in[20];
    const float* eps      = (const float*)d_in[21];
    const int* input_ids  = (const int*)d_in[22];
    const int* target_ids = (const int*)d_in[23];
    const int* p_ic       = (const int*)d_in[24];
    const int* p_tc       = (const int*)d_in[25];

    float* ws      = (float*)d_ws;
    float* pre_enc = ws;                        // 256*4096
    float* pre_dec = pre_enc + (size_t)TT * G4; // 256*4096
    float* hs      = pre_dec + (size_t)TT * G4; // 256*1024
    float* h_buf   = hs + (size_t)TT * HD;      // 2*1024
    float* z_buf   = h_buf + 2 * HD;            // 256

    float* outp     = (float*)d_out;
    float* out_mlgv = outp + (size_t)TT * VOC;

    hipLaunchKernelGGL(k_pre, dim3(256), dim3(256), 0, stream,
                       enc_emb, input_ids, enc_wih, enc_bih, enc_bhh, pre_enc, 0);
    hipLaunchKernelGGL(k_pre, dim3(256), dim3(256), 0, stream,
                       dec_emb, target_ids, dec_wih, dec_bih, dec_bhh, pre_dec, 1);

    void* args[] = {
        (void*)&cond_emb, (void*)&enc_whh, (void*)&mean_w, (void*)&mean_b,
        (void*)&lgv_w, (void*)&lgv_b, (void*)&l2h_w, (void*)&l2h_b,
        (void*)&l2c_w, (void*)&l2c_b, (void*)&dec_whh, (void*)&eps,
        (void*)&p_ic, (void*)&p_tc, (void*)&pre_enc, (void*)&pre_dec,
        (void*)&h_buf, (void*)&z_buf, (void*)&hs, (void*)&out_mlgv
    };
    hipLaunchCooperativeKernel((const void*)k_seq, dim3(128), dim3(256),
                               args, 0, stream);

    hipLaunchKernelGGL(k_out, dim3(2000), dim3(256), 0, stream,
                       hs, out_w, out_b, outp);
}

// Round 3
// 8356.877 us; speedup vs baseline: 1.0561x; 1.0561x over previous
//
#include <hip/hip_runtime.h>
#include <hip/hip_bf16.h>

#define HD   1024
#define G4   4096
#define CND  64
#define LAT  256
#define VOC  32000
#define TT   256
#define ZCN  320   // LAT + CND
#define NWG  128   // k_seq workgroups

__device__ __forceinline__ float sigf(float x) { return 1.0f / (1.0f + expf(-x)); }

// ---------------------------------------------------------------------------
// Hand-rolled grid barrier: one atomicAdd + one poller per WG.
// Counter is zeroed by hipMemsetAsync before each launch (graph-safe).
// Release: h-writers (tid<8) and arriver (tid0) share wave 0 -> program order
// + __threadfence() orders the h stores before the counter increment.
// Acquire: all threads fence after the exit __syncthreads.
// ---------------------------------------------------------------------------
__device__ __forceinline__ void gbar(unsigned* cnt, unsigned target, int tid)
{
    __syncthreads();
    if (tid == 0) {
        __threadfence();                       // release: drain + make h visible
        atomicAdd(cnt, 1u);                    // device-scope arrival
        while (__hip_atomic_load(cnt, __ATOMIC_RELAXED,
                                 __HIP_MEMORY_SCOPE_AGENT) < target) {
            __builtin_amdgcn_s_sleep(1);       // ~64-cycle backoff
        }
    }
    __syncthreads();
    __threadfence();                           // acquire: invalidate stale lines
}

// ---------------------------------------------------------------------------
// k_pre: pre[t][n] = dot(emb[ids[t]], wih[n]) + bih[n] + bhh[n]
// M=256 (t), N=4096 (gate rows), K=1024.  64x64 tiles, BK=32, 256 threads.
// ---------------------------------------------------------------------------
__global__ __launch_bounds__(256) void k_pre(
    const float* __restrict__ emb, const int* __restrict__ ids,
    const float* __restrict__ wih, const float* __restrict__ bih,
    const float* __restrict__ bhh, float* __restrict__ pre, int shift)
{
    __shared__ float As[64 * 36];
    __shared__ float Bs[64 * 36];
    __shared__ int ids_s[64];

    const int bid = blockIdx.x;
    const int m0 = (bid >> 6) * 64;
    const int n0 = (bid & 63) * 64;
    const int tid = threadIdx.x;

    if (tid < 64) {
        int t = m0 + tid;
        ids_s[tid] = shift ? ((t == 0) ? 0 : ids[t - 1]) : ids[t];
    }
    __syncthreads();

    const int r  = tid >> 2;
    const int c0 = (tid & 3) * 8;
    const int ty = tid >> 4, tx = tid & 15;

    float acc[4][4] = {};

    for (int k0 = 0; k0 < HD; k0 += 32) {
        __syncthreads();
        {
            const float4* pa = (const float4*)(emb + (size_t)ids_s[r] * HD + k0 + c0);
            float4 a0 = pa[0], a1 = pa[1];
            float* d = &As[r * 36 + c0];
            d[0] = a0.x; d[1] = a0.y; d[2] = a0.z; d[3] = a0.w;
            d[4] = a1.x; d[5] = a1.y; d[6] = a1.z; d[7] = a1.w;
            const float4* pb = (const float4*)(wih + (size_t)(n0 + r) * HD + k0 + c0);
            float4 b0 = pb[0], b1 = pb[1];
            float* e = &Bs[r * 36 + c0];
            e[0] = b0.x; e[1] = b0.y; e[2] = b0.z; e[3] = b0.w;
            e[4] = b1.x; e[5] = b1.y; e[6] = b1.z; e[7] = b1.w;
        }
        __syncthreads();
        #pragma unroll
        for (int kk = 0; kk < 32; ++kk) {
            float a[4], b[4];
            #pragma unroll
            for (int i = 0; i < 4; ++i) a[i] = As[(ty * 4 + i) * 36 + kk];
            #pragma unroll
            for (int j = 0; j < 4; ++j) b[j] = Bs[(tx * 4 + j) * 36 + kk];
            #pragma unroll
            for (int i = 0; i < 4; ++i)
                #pragma unroll
                for (int j = 0; j < 4; ++j)
                    acc[i][j] = fmaf(a[i], b[j], acc[i][j]);
        }
    }

    #pragma unroll
    for (int j = 0; j < 4; ++j) {
        int n = n0 + tx * 4 + j;
        float bias = bih[n] + bhh[n];
        #pragma unroll
        for (int i = 0; i < 4; ++i) {
            int m = m0 + ty * 4 + i;
            pre[(size_t)m * G4 + n] = acc[i][j] + bias;
        }
    }
}

// ---------------------------------------------------------------------------
// k_out: logits[t][n] = dot(hs[t], out_w[n]) + out_b[n]   (fp32 out)
// M=256, N=32000, K=1024. 64x64 tiles -> grid = 4*500 = 2000 blocks.
// ---------------------------------------------------------------------------
__global__ __launch_bounds__(256) void k_out(
    const float* __restrict__ hs, const float* __restrict__ ow,
    const float* __restrict__ ob, float* __restrict__ outp)
{
    __shared__ float As[64 * 36];
    __shared__ float Bs[64 * 36];

    const int bid = blockIdx.x;
    const int m0 = (bid / 500) * 64;
    const int n0 = (bid % 500) * 64;
    const int tid = threadIdx.x;

    const int r  = tid >> 2;
    const int c0 = (tid & 3) * 8;
    const int ty = tid >> 4, tx = tid & 15;

    float acc[4][4] = {};

    for (int k0 = 0; k0 < HD; k0 += 32) {
        __syncthreads();
        {
            const float4* pa = (const float4*)(hs + (size_t)(m0 + r) * HD + k0 + c0);
            float4 a0 = pa[0], a1 = pa[1];
            float* d = &As[r * 36 + c0];
            d[0] = a0.x; d[1] = a0.y; d[2] = a0.z; d[3] = a0.w;
            d[4] = a1.x; d[5] = a1.y; d[6] = a1.z; d[7] = a1.w;
            const float4* pb = (const float4*)(ow + (size_t)(n0 + r) * HD + k0 + c0);
            float4 b0 = pb[0], b1 = pb[1];
            float* e = &Bs[r * 36 + c0];
            e[0] = b0.x; e[1] = b0.y; e[2] = b0.z; e[3] = b0.w;
            e[4] = b1.x; e[5] = b1.y; e[6] = b1.z; e[7] = b1.w;
        }
        __syncthreads();
        #pragma unroll
        for (int kk = 0; kk < 32; ++kk) {
            float a[4], b[4];
            #pragma unroll
            for (int i = 0; i < 4; ++i) a[i] = As[(ty * 4 + i) * 36 + kk];
            #pragma unroll
            for (int j = 0; j < 4; ++j) b[j] = Bs[(tx * 4 + j) * 36 + kk];
            #pragma unroll
            for (int i = 0; i < 4; ++i)
                #pragma unroll
                for (int j = 0; j < 4; ++j)
                    acc[i][j] = fmaf(a[i], b[j], acc[i][j]);
        }
    }

    #pragma unroll
    for (int j = 0; j < 4; ++j) {
        int n = n0 + tx * 4 + j;
        float bias = ob[n];
        #pragma unroll
        for (int i = 0; i < 4; ++i) {
            int m = m0 + ty * 4 + i;
            outp[(size_t)m * VOC + n] = acc[i][j] + bias;
        }
    }
}

// ---------------------------------------------------------------------------
// k_seq: 128 WGs x 256 threads. WG w owns h-rows [w*8, w*8+8).
// rl = tid>>3 (0..31): gate = rl>>3, jl = rl&7, row = gate*1024 + w*8 + jl.
// s = tid&7 = k-slice (128 consecutive k).  128 fp32 whh weights in VGPRs.
// Per step: preload pre[t] (overlaps barrier spin), gbar, stage h to LDS
// (padded), 128 FMA (4 accs), 8-lane shuffle reduce, gate math on 8 threads.
// ---------------------------------------------------------------------------
__device__ __forceinline__ void load_w(float4 (&wreg)[32], const float* w,
                                       int row, int s)
{
    const float4* p = (const float4*)(w + (size_t)row * HD + s * 128);
    #pragma unroll
    for (int u = 0; u < 32; ++u) wreg[u] = p[u];
}

__device__ __forceinline__ void lstm_loop(
    const float4 (&wreg)[32], const float* __restrict__ pre,
    float* __restrict__ h_buf, float* __restrict__ hs, float& c_reg,
    float* h_lds, float* g_lds, int tid, int s, int rl, int row, int j_own,
    unsigned* cnt, unsigned& bar)
{
    for (int t = 0; t < TT; ++t) {
        // issue pre load BEFORE the barrier: latency hides under the spin
        float pv = 0.f;
        if (s == 0) pv = pre[(size_t)t * G4 + row];

        ++bar; gbar(cnt, NWG * bar, tid);

        const float4* hb4 = (const float4*)(h_buf + (t & 1) * HD);
        ((float4*)h_lds)[(tid >> 5) * 33 + (tid & 31)] = hb4[tid];
        __syncthreads();
        const float4* h4 = (const float4*)h_lds;
        float a0 = 0.f, a1 = 0.f, a2 = 0.f, a3 = 0.f;
        #pragma unroll
        for (int u = 0; u < 32; ++u) {
            float4 wv = wreg[u];
            float4 hv = h4[s * 33 + u];
            a0 = fmaf(wv.x, hv.x, a0);
            a1 = fmaf(wv.y, hv.y, a1);
            a2 = fmaf(wv.z, hv.z, a2);
            a3 = fmaf(wv.w, hv.w, a3);
        }
        float acc = (a0 + a1) + (a2 + a3);
        acc += __shfl_xor(acc, 1);
        acc += __shfl_xor(acc, 2);
        acc += __shfl_xor(acc, 4);
        if (s == 0) g_lds[rl] = acc + pv;
        __syncthreads();
        if (tid < 8) {
            float xi = g_lds[tid],      xf = g_lds[8 + tid];
            float xg = g_lds[16 + tid], xo = g_lds[24 + tid];
            c_reg = sigf(xf) * c_reg + sigf(xi) * tanhf(xg);
            float hv = sigf(xo) * tanhf(c_reg);
            h_buf[((t + 1) & 1) * HD + j_own] = hv;
            if (hs) hs[(size_t)t * HD + j_own] = hv;
        }
    }
}

__global__ __launch_bounds__(256, 1) void k_seq(
    const float* __restrict__ cond_emb, const float* __restrict__ enc_whh,
    const float* __restrict__ mean_w, const float* __restrict__ mean_b,
    const float* __restrict__ lgv_w, const float* __restrict__ lgv_b,
    const float* __restrict__ l2h_w, const float* __restrict__ l2h_b,
    const float* __restrict__ l2c_w, const float* __restrict__ l2c_b,
    const float* __restrict__ dec_whh, const float* __restrict__ eps,
    const int* __restrict__ p_ic, const int* __restrict__ p_tc,
    const float* __restrict__ pre_enc, const float* __restrict__ pre_dec,
    float* __restrict__ h_buf, float* __restrict__ z_buf,
    float* __restrict__ hs, float* __restrict__ out_mlgv,
    unsigned* bar_cnt)
{
    __shared__ float h_lds[8 * 132];
    __shared__ float g_lds[32];
    __shared__ float red[16];
    __shared__ float sm[4];

    const int w   = blockIdx.x;        // 0..127
    const int tid = threadIdx.x;
    const int s   = tid & 7;
    const int rl  = tid >> 3;
    const int gate = rl >> 3;
    const int jl   = rl & 7;
    const int row  = gate * HD + w * 8 + jl;
    const int j_own = w * 8 + tid;     // valid for tid<8
    float c_reg = 0.f;
    unsigned bar = 0;

    // ---- encoder initial hidden: zeros(H-C) ++ cond_emb[input_c] ----
    if (tid < 8) {
        int j = w * 8 + tid;
        float v = 0.f;
        int ic = p_ic[0];
        if (j >= HD - CND) v = cond_emb[ic * CND + (j - (HD - CND))];
        h_buf[j] = v;   // buffer 0
    }

    float4 wreg[32];
    load_w(wreg, enc_whh, row, s);
    lstm_loop(wreg, pre_enc, h_buf, nullptr, c_reg,
              h_lds, g_lds, tid, s, rl, row, j_own, bar_cnt, bar);

    ++bar; gbar(bar_cnt, NWG * bar, tid);   // hT visible (buffer 0)

    // ---- latent 1: m, lgv, z ----
    ((float4*)h_lds)[tid] = ((const float4*)h_buf)[tid];
    __syncthreads();
    {
        int d = tid >> 6;              // 0..3
        int l64 = tid & 63;
        int l = w * 2 + (d & 1);
        const float* wrow = (d < 2 ? mean_w : lgv_w) + (size_t)l * HD;
        float acc = 0.f;
        #pragma unroll
        for (int e = 0; e < 16; ++e) {
            int k = e * 64 + l64;
            acc = fmaf(wrow[k], h_lds[k], acc);
        }
        #pragma unroll
        for (int o = 32; o >= 1; o >>= 1) acc += __shfl_xor(acc, o);
        if (l64 == 0) sm[d] = acc + (d < 2 ? mean_b : lgv_b)[l];
    }
    __syncthreads();
    if (tid < 2) {
        int l = w * 2 + tid;
        float m = sm[tid], lg = sm[2 + tid];
        float z = eps[l] * expf(0.5f * lg) + m;
        z_buf[l] = z;
        out_mlgv[l]       = m;
        out_mlgv[LAT + l] = lg;
    }

    ++bar; gbar(bar_cnt, NWG * bar, tid);   // z_buf visible

    // ---- latent 2: zc = [z, cond_emb[target_c]] -> dh0, dc0 ----
    {
        int tc = p_tc[0];
        for (int idx = tid; idx < ZCN; idx += 256)
            h_lds[idx] = (idx < LAT) ? z_buf[idx]
                                     : cond_emb[tc * CND + idx - LAT];
    }
    __syncthreads();
    {
        int r2 = tid >> 4;             // 0..15 (8 dh rows + 8 dc rows)
        int l16 = tid & 15;
        int which = r2 >> 3;
        int i = w * 8 + (r2 & 7);
        const float* wrow = (which ? l2c_w : l2h_w) + (size_t)i * ZCN;
        float acc = 0.f;
        #pragma unroll
        for (int e = 0; e < 20; ++e) {
            int k = e * 16 + l16;
            acc = fmaf(wrow[k], h_lds[k], acc);
        }
        acc += __shfl_xor(acc, 1);
        acc += __shfl_xor(acc, 2);
        acc += __shfl_xor(acc, 4);
        acc += __shfl_xor(acc, 8);
        if (l16 == 0) red[r2] = acc + (which ? l2c_b : l2h_b)[i];
    }
    __syncthreads();
    if (tid < 8) {
        h_buf[j_own] = red[tid];       // dh0 into buffer 0
        c_reg = red[8 + tid];          // dc0
    }

    load_w(wreg, dec_whh, row, s);
    lstm_loop(wreg, pre_dec, h_buf, hs, c_reg,
              h_lds, g_lds, tid, s, rl, row, j_own, bar_cnt, bar);
}

// ---------------------------------------------------------------------------
extern "C" void kernel_launch(void* const* d_in, const int* in_sizes, int n_in,
                              void* d_out, int out_size, void* d_ws, size_t ws_size,
                              hipStream_t stream)
{
    const float* cond_emb = (const float*)d_in[0];
    const float* enc_emb  = (const float*)d_in[1];
    const float* enc_wih  = (const float*)d_in[2];
    const float* enc_whh  = (const float*)d_in[3];
    const float* enc_bih  = (const float*)d_in[4];
    const float* enc_bhh  = (const float*)d_in[5];
    const float* mean_w   = (const float*)d_in[6];
    const float* mean_b   = (const float*)d_in[7];
    const float* lgv_w    = (const float*)d_in[8];
    const float* lgv_b    = (const float*)d_in[9];
    const float* l2h_w    = (const float*)d_in[10];
    const float* l2h_b    = (const float*)d_in[11];
    const float* l2c_w    = (const float*)d_in[12];
    const float* l2c_b    = (const float*)d_in[13];
    const float* dec_emb  = (const float*)d_in[14];
    const float* dec_wih  = (const float*)d_in[15];
    const float* dec_whh  = (const float*)d_in[16];
    const float* dec_bih  = (const float*)d_in[17];
    const float* dec_bhh  = (const float*)d_in[18];
    const float* out_w    = (const float*)d_in[19];
    const float* out_b    = (const float*)d_in[20];
    const float* eps      = (const float*)d_in[21];
    const int* input_ids  = (const int*)d_in[22];
    const int* target_ids = (const int*)d_in[23];
    const int* p_ic       = (const int*)d_in[24];
    const int* p_tc       = (const int*)d_in[25];

    float* ws      = (float*)d_ws;
    float* pre_enc = ws;                        // 256*4096
    float* pre_dec = pre_enc + (size_t)TT * G4; // 256*4096
    float* hs      = pre_dec + (size_t)TT * G4; // 256*1024
    float* h_buf   = hs + (size_t)TT * HD;      // 2*1024
    float* z_buf   = h_buf + 2 * HD;            // 256
    unsigned* bar_cnt = (unsigned*)(z_buf + LAT);

    float* outp     = (float*)d_out;
    float* out_mlgv = outp + (size_t)TT * VOC;

    hipMemsetAsync(bar_cnt, 0, 128, stream);    // reset barrier counter

    hipLaunchKernelGGL(k_pre, dim3(256), dim3(256), 0, stream,
                       enc_emb, input_ids, enc_wih, enc_bih, enc_bhh, pre_enc, 0);
    hipLaunchKernelGGL(k_pre, dim3(256), dim3(256), 0, stream,
                       dec_emb, target_ids, dec_wih, dec_bih, dec_bhh, pre_dec, 1);

    void* args[] = {
        (void*)&cond_emb, (void*)&enc_whh, (void*)&mean_w, (void*)&mean_b,
        (void*)&lgv_w, (void*)&lgv_b, (void*)&l2h_w, (void*)&l2h_b,
        (void*)&l2c_w, (void*)&l2c_b, (void*)&dec_whh, (void*)&eps,
        (void*)&p_ic, (void*)&p_tc, (void*)&pre_enc, (void*)&pre_dec,
        (void*)&h_buf, (void*)&z_buf, (void*)&hs, (void*)&out_mlgv,
        (void*)&bar_cnt
    };
    hipLaunchCooperativeKernel((const void*)k_seq, dim3(NWG), dim3(256),
                               args, 0, stream);

    hipLaunchKernelGGL(k_out, dim3(2000), dim3(256), 0, stream,
                       hs, out_w, out_b, outp);
}

// Round 4
// 2112.304 us; speedup vs baseline: 4.1782x; 3.9563x over previous
//
#include <hip/hip_runtime.h>
#include <hip/hip_bf16.h>

#define HD   1024
#define G4   4096
#define CND  64
#define LAT  256
#define VOC  32000
#define TT   256
#define ZCN  320    // LAT + CND
#define NWG  128
#define DEC0 301u   // decoder h version base (encoder uses 1..257)

typedef unsigned long long u64;

__device__ __forceinline__ float sigf(float x) { return 1.0f / (1.0f + expf(-x)); }

__device__ __forceinline__ u64 al64(const u64* p) {
    return __hip_atomic_load((u64*)p, __ATOMIC_RELAXED, __HIP_MEMORY_SCOPE_AGENT);
}
__device__ __forceinline__ void as64(u64* p, u64 v) {
    __hip_atomic_store(p, v, __ATOMIC_RELAXED, __HIP_MEMORY_SCOPE_AGENT);
}
__device__ __forceinline__ u64 packhv(float h, unsigned tag) {
    return ((u64)tag << 32) | (u64)__float_as_uint(h);
}

// ---------------------------------------------------------------------------
// k_pre: pre[t][n] = dot(emb[ids[t]], wih[n]) + bih[n] + bhh[n]
// ---------------------------------------------------------------------------
__global__ __launch_bounds__(256) void k_pre(
    const float* __restrict__ emb, const int* __restrict__ ids,
    const float* __restrict__ wih, const float* __restrict__ bih,
    const float* __restrict__ bhh, float* __restrict__ pre, int shift)
{
    __shared__ float As[64 * 36];
    __shared__ float Bs[64 * 36];
    __shared__ int ids_s[64];

    const int bid = blockIdx.x;
    const int m0 = (bid >> 6) * 64;
    const int n0 = (bid & 63) * 64;
    const int tid = threadIdx.x;

    if (tid < 64) {
        int t = m0 + tid;
        ids_s[tid] = shift ? ((t == 0) ? 0 : ids[t - 1]) : ids[t];
    }
    __syncthreads();

    const int r  = tid >> 2;
    const int c0 = (tid & 3) * 8;
    const int ty = tid >> 4, tx = tid & 15;

    float acc[4][4] = {};

    for (int k0 = 0; k0 < HD; k0 += 32) {
        __syncthreads();
        {
            const float4* pa = (const float4*)(emb + (size_t)ids_s[r] * HD + k0 + c0);
            float4 a0 = pa[0], a1 = pa[1];
            float* d = &As[r * 36 + c0];
            d[0] = a0.x; d[1] = a0.y; d[2] = a0.z; d[3] = a0.w;
            d[4] = a1.x; d[5] = a1.y; d[6] = a1.z; d[7] = a1.w;
            const float4* pb = (const float4*)(wih + (size_t)(n0 + r) * HD + k0 + c0);
            float4 b0 = pb[0], b1 = pb[1];
            float* e = &Bs[r * 36 + c0];
            e[0] = b0.x; e[1] = b0.y; e[2] = b0.z; e[3] = b0.w;
            e[4] = b1.x; e[5] = b1.y; e[6] = b1.z; e[7] = b1.w;
        }
        __syncthreads();
        #pragma unroll
        for (int kk = 0; kk < 32; ++kk) {
            float a[4], b[4];
            #pragma unroll
            for (int i = 0; i < 4; ++i) a[i] = As[(ty * 4 + i) * 36 + kk];
            #pragma unroll
            for (int j = 0; j < 4; ++j) b[j] = Bs[(tx * 4 + j) * 36 + kk];
            #pragma unroll
            for (int i = 0; i < 4; ++i)
                #pragma unroll
                for (int j = 0; j < 4; ++j)
                    acc[i][j] = fmaf(a[i], b[j], acc[i][j]);
        }
    }

    #pragma unroll
    for (int j = 0; j < 4; ++j) {
        int n = n0 + tx * 4 + j;
        float bias = bih[n] + bhh[n];
        #pragma unroll
        for (int i = 0; i < 4; ++i) {
            int m = m0 + ty * 4 + i;
            pre[(size_t)m * G4 + n] = acc[i][j] + bias;
        }
    }
}

// ---------------------------------------------------------------------------
// k_out: logits[t][n] = dot(hs[t], out_w[n]) + out_b[n]
// ---------------------------------------------------------------------------
__global__ __launch_bounds__(256) void k_out(
    const float* __restrict__ hs, const float* __restrict__ ow,
    const float* __restrict__ ob, float* __restrict__ outp)
{
    __shared__ float As[64 * 36];
    __shared__ float Bs[64 * 36];

    const int bid = blockIdx.x;
    const int m0 = (bid / 500) * 64;
    const int n0 = (bid % 500) * 64;
    const int tid = threadIdx.x;

    const int r  = tid >> 2;
    const int c0 = (tid & 3) * 8;
    const int ty = tid >> 4, tx = tid & 15;

    float acc[4][4] = {};

    for (int k0 = 0; k0 < HD; k0 += 32) {
        __syncthreads();
        {
            const float4* pa = (const float4*)(hs + (size_t)(m0 + r) * HD + k0 + c0);
            float4 a0 = pa[0], a1 = pa[1];
            float* d = &As[r * 36 + c0];
            d[0] = a0.x; d[1] = a0.y; d[2] = a0.z; d[3] = a0.w;
            d[4] = a1.x; d[5] = a1.y; d[6] = a1.z; d[7] = a1.w;
            const float4* pb = (const float4*)(ow + (size_t)(n0 + r) * HD + k0 + c0);
            float4 b0 = pb[0], b1 = pb[1];
            float* e = &Bs[r * 36 + c0];
            e[0] = b0.x; e[1] = b0.y; e[2] = b0.z; e[3] = b0.w;
            e[4] = b1.x; e[5] = b1.y; e[6] = b1.z; e[7] = b1.w;
        }
        __syncthreads();
        #pragma unroll
        for (int kk = 0; kk < 32; ++kk) {
            float a[4], b[4];
            #pragma unroll
            for (int i = 0; i < 4; ++i) a[i] = As[(ty * 4 + i) * 36 + kk];
            #pragma unroll
            for (int j = 0; j < 4; ++j) b[j] = Bs[(tx * 4 + j) * 36 + kk];
            #pragma unroll
            for (int i = 0; i < 4; ++i)
                #pragma unroll
                for (int j = 0; j < 4; ++j)
                    acc[i][j] = fmaf(a[i], b[j], acc[i][j]);
        }
    }

    #pragma unroll
    for (int j = 0; j < 4; ++j) {
        int n = n0 + tx * 4 + j;
        float bias = ob[n];
        #pragma unroll
        for (int i = 0; i < 4; ++i) {
            int m = m0 + ty * 4 + i;
            outp[(size_t)m * VOC + n] = acc[i][j] + bias;
        }
    }
}

// ---------------------------------------------------------------------------
// k_seq: 128 WGs x 256 threads, fence-free tagged-mailbox dataflow.
// mb[slot][j] = {tag(=h version), fp32 h_j}, slot = version&1, agent-scope 8B
// atomics (bypass per-XCD L2, live in Infinity Cache).  WG w owns rows
// [w*8, w*8+8).  whh slice staged in LDS (132KB), quad-balanced layout.
// ---------------------------------------------------------------------------
#define WROW 1060   // LDS row stride (floats); 1060%32=4 -> bank-quad spread
#define WCH  132    // LDS chunk stride (floats) for 128-float k-chunks

__device__ __forceinline__ void stage_w(const float* __restrict__ whh, int w,
                                        float* w_lds, int tid)
{
    #pragma unroll
    for (int r = 0; r < 32; ++r) {
        int gate = r >> 3, jl = r & 7;
        const float4* src = (const float4*)(whh + (size_t)(gate * HD + w * 8 + jl) * HD);
        float4 v = src[tid];
        *(float4*)&w_lds[r * WROW + (tid >> 5) * WCH + (tid & 31) * 4] = v;
    }
}

// poll own 4 elements of version v, deposit into padded h_lds
__device__ __forceinline__ void read_h(const u64* mb, unsigned v,
                                       float* h_lds, int tid)
{
    const u64* p = mb + (size_t)(v & 1u) * HD + tid * 4;
    u64 e0, e1, e2, e3;
    for (;;) {
        e0 = al64(p); e1 = al64(p + 1); e2 = al64(p + 2); e3 = al64(p + 3);
        if ((unsigned)(e0 >> 32) >= v && (unsigned)(e1 >> 32) >= v &&
            (unsigned)(e2 >> 32) >= v && (unsigned)(e3 >> 32) >= v) break;
        __builtin_amdgcn_s_sleep(1);
    }
    float4 hv = make_float4(__uint_as_float((unsigned)e0),
                            __uint_as_float((unsigned)e1),
                            __uint_as_float((unsigned)e2),
                            __uint_as_float((unsigned)e3));
    *(float4*)&h_lds[(tid >> 5) * WCH + (tid & 31) * 4] = hv;
}

__device__ __forceinline__ void lstm_loop(
    const float* __restrict__ pre, u64* mb, float* __restrict__ hs,
    float& c_reg, const float* w_lds, float* h_lds, float* g_lds,
    int tid, int s, int rl, int row, int j_own, unsigned vbase)
{
    for (int t = 0; t < TT; ++t) {
        unsigned v = vbase + (unsigned)t;
        float pv = 0.f;
        if (s == 0) pv = pre[(size_t)t * G4 + row];   // hides under poll

        read_h(mb, v, h_lds, tid);
        __syncthreads();

        const float* wr = w_lds + rl * WROW + s * WCH;
        const float* hr = h_lds + s * WCH;
        float a0 = 0.f, a1 = 0.f, a2 = 0.f, a3 = 0.f;
        #pragma unroll
        for (int u = 0; u < 32; ++u) {
            float4 wv = *(const float4*)(wr + u * 4);
            float4 hv = *(const float4*)(hr + u * 4);
            a0 = fmaf(wv.x, hv.x, a0);
            a1 = fmaf(wv.y, hv.y, a1);
            a2 = fmaf(wv.z, hv.z, a2);
            a3 = fmaf(wv.w, hv.w, a3);
        }
        float acc = (a0 + a1) + (a2 + a3);
        acc += __shfl_xor(acc, 1);
        acc += __shfl_xor(acc, 2);
        acc += __shfl_xor(acc, 4);
        if (s == 0) g_lds[rl] = acc + pv;
        __syncthreads();

        if (tid < 8) {
            float xi = g_lds[tid],      xf = g_lds[8 + tid];
            float xg = g_lds[16 + tid], xo = g_lds[24 + tid];
            c_reg = sigf(xf) * c_reg + sigf(xi) * tanhf(xg);
            float hv = sigf(xo) * tanhf(c_reg);
            as64(&mb[(size_t)((v + 1u) & 1u) * HD + j_own], packhv(hv, v + 1u));
            if (hs) hs[(size_t)t * HD + j_own] = hv;
        }
    }
}

__global__ __launch_bounds__(256, 1) void k_seq(
    const float* __restrict__ cond_emb, const float* __restrict__ enc_whh,
    const float* __restrict__ mean_w, const float* __restrict__ mean_b,
    const float* __restrict__ lgv_w, const float* __restrict__ lgv_b,
    const float* __restrict__ l2h_w, const float* __restrict__ l2h_b,
    const float* __restrict__ l2c_w, const float* __restrict__ l2c_b,
    const float* __restrict__ dec_whh, const float* __restrict__ eps,
    const int* __restrict__ p_ic, const int* __restrict__ p_tc,
    const float* __restrict__ pre_enc, const float* __restrict__ pre_dec,
    u64* mb, u64* zmb,
    float* __restrict__ hs, float* __restrict__ out_mlgv)
{
    __shared__ float w_lds[32 * WROW];   // 135,680 B
    __shared__ float h_lds[8 * WCH];     //   4,224 B
    __shared__ float g_lds[32];
    __shared__ float red[16];
    __shared__ float sm[4];

    const int w   = blockIdx.x;          // 0..127
    const int tid = threadIdx.x;
    const int s   = tid & 7;             // k-slice
    const int rl  = tid >> 3;            // 0..31
    const int gate = rl >> 3;
    const int jl   = rl & 7;
    const int row  = gate * HD + w * 8 + jl;
    const int j_own = w * 8 + tid;       // valid for tid<8
    float c_reg = 0.f;

    // ---- publish initial h (version 1): zeros(H-C) ++ cond_emb[input_c] ----
    if (tid < 8) {
        int j = j_own;
        float v0 = 0.f;
        int ic = p_ic[0];
        if (j >= HD - CND) v0 = cond_emb[ic * CND + (j - (HD - CND))];
        as64(&mb[(size_t)1 * HD + j], packhv(v0, 1u));   // slot 1&1 = 1
    }

    stage_w(enc_whh, w, w_lds, tid);
    lstm_loop(pre_enc, mb, nullptr, c_reg, w_lds, h_lds, g_lds,
              tid, s, rl, row, j_own, 1u);

    // ---- latent 1: read hT (version TT+1 = 257), compute m, lgv, z ----
    read_h(mb, TT + 1u, h_lds, tid);
    __syncthreads();
    {
        int d = tid >> 6;                // 0..3
        int l64 = tid & 63;
        int l = w * 2 + (d & 1);
        const float* wrow = (d < 2 ? mean_w : lgv_w) + (size_t)l * HD;
        float acc = 0.f;
        #pragma unroll
        for (int e = 0; e < 16; ++e) {
            int k = e * 64 + l64;
            acc = fmaf(wrow[k], h_lds[(k >> 7) * WCH + (k & 127)], acc);
        }
        #pragma unroll
        for (int o = 32; o >= 1; o >>= 1) acc += __shfl_xor(acc, o);
        if (l64 == 0) sm[d] = acc + (d < 2 ? mean_b : lgv_b)[l];
    }
    __syncthreads();
    if (tid < 2) {
        int l = w * 2 + tid;
        float m = sm[tid], lg = sm[2 + tid];
        float z = eps[l] * expf(0.5f * lg) + m;
        as64(&zmb[l], packhv(z, 1u));
        out_mlgv[l]       = m;
        out_mlgv[LAT + l] = lg;
    }

    // ---- latent 2: poll z, build zc in LDS, compute dh0/dc0 ----
    {
        u64 e;
        const u64* p = zmb + tid;        // tid 0..255 covers all of z
        do { e = al64(p); } while ((unsigned)(e >> 32) < 1u);
        h_lds[tid] = __uint_as_float((unsigned)e);
    }
    if (tid < CND) {
        int tc = p_tc[0];
        h_lds[LAT + tid] = cond_emb[tc * CND + tid];
    }
    __syncthreads();
    {
        int r2 = tid >> 4;               // 0..15 (8 dh rows + 8 dc rows)
        int l16 = tid & 15;
        int which = r2 >> 3;
        int i = w * 8 + (r2 & 7);
        const float* wrow = (which ? l2c_w : l2h_w) + (size_t)i * ZCN;
        float acc = 0.f;
        #pragma unroll
        for (int e = 0; e < 20; ++e) {
            int k = e * 16 + l16;
            acc = fmaf(wrow[k], h_lds[k], acc);
        }
        acc += __shfl_xor(acc, 1);
        acc += __shfl_xor(acc, 2);
        acc += __shfl_xor(acc, 4);
        acc += __shfl_xor(acc, 8);
        if (l16 == 0) red[r2] = acc + (which ? l2c_b : l2h_b)[i];
    }
    __syncthreads();
    if (tid < 8) {
        // publish dh0 as version DEC0 (slot DEC0&1 = 1); safe: all WGs have
        // passed latent-1 (z handoff gates slot reuse)
        as64(&mb[(size_t)(DEC0 & 1u) * HD + j_own], packhv(red[tid], DEC0));
        c_reg = red[8 + tid];            // dc0
    }

    stage_w(dec_whh, w, w_lds, tid);     // LDS reuse safe: WG-local, loop syncs
    lstm_loop(pre_dec, mb, hs, c_reg, w_lds, h_lds, g_lds,
              tid, s, rl, row, j_own, DEC0);
}

// ---------------------------------------------------------------------------
extern "C" void kernel_launch(void* const* d_in, const int* in_sizes, int n_in,
                              void* d_out, int out_size, void* d_ws, size_t ws_size,
                              hipStream_t stream)
{
    const float* cond_emb = (const float*)d_in[0];
    const float* enc_emb  = (const float*)d_in[1];
    const float* enc_wih  = (const float*)d_in[2];
    const float* enc_whh  = (const float*)d_in[3];
    const float* enc_bih  = (const float*)d_in[4];
    const float* enc_bhh  = (const float*)d_in[5];
    const float* mean_w   = (const float*)d_in[6];
    const float* mean_b   = (const float*)d_in[7];
    const float* lgv_w    = (const float*)d_in[8];
    const float* lgv_b    = (const float*)d_in[9];
    const float* l2h_w    = (const float*)d_in[10];
    const float* l2h_b    = (const float*)d_in[11];
    const float* l2c_w    = (const float*)d_in[12];
    const float* l2c_b    = (const float*)d_in[13];
    const float* dec_emb  = (const float*)d_in[14];
    const float* dec_wih  = (const float*)d_in[15];
    const float* dec_whh  = (const float*)d_in[16];
    const float* dec_bih  = (const float*)d_in[17];
    const float* dec_bhh  = (const float*)d_in[18];
    const float* out_w    = (const float*)d_in[19];
    const float* out_b    = (const float*)d_in[20];
    const float* eps      = (const float*)d_in[21];
    const int* input_ids  = (const int*)d_in[22];
    const int* target_ids = (const int*)d_in[23];
    const int* p_ic       = (const int*)d_in[24];
    const int* p_tc       = (const int*)d_in[25];

    float* ws      = (float*)d_ws;
    float* pre_enc = ws;                        // 256*4096
    float* pre_dec = pre_enc + (size_t)TT * G4; // 256*4096
    float* hs      = pre_dec + (size_t)TT * G4; // 256*1024
    u64*   mb      = (u64*)(hs + (size_t)TT * HD);  // 2*1024 entries
    u64*   zmb     = mb + 2 * HD;               // 256 entries

    float* outp     = (float*)d_out;
    float* out_mlgv = outp + (size_t)TT * VOC;

    // reset mailbox tags (deterministic across graph replays)
    hipMemsetAsync(mb, 0, (2 * HD + LAT) * sizeof(u64), stream);

    hipLaunchKernelGGL(k_pre, dim3(256), dim3(256), 0, stream,
                       enc_emb, input_ids, enc_wih, enc_bih, enc_bhh, pre_enc, 0);
    hipLaunchKernelGGL(k_pre, dim3(256), dim3(256), 0, stream,
                       dec_emb, target_ids, dec_wih, dec_bih, dec_bhh, pre_dec, 1);

    void* args[] = {
        (void*)&cond_emb, (void*)&enc_whh, (void*)&mean_w, (void*)&mean_b,
        (void*)&lgv_w, (void*)&lgv_b, (void*)&l2h_w, (void*)&l2h_b,
        (void*)&l2c_w, (void*)&l2c_b, (void*)&dec_whh, (void*)&eps,
        (void*)&p_ic, (void*)&p_tc, (void*)&pre_enc, (void*)&pre_dec,
        (void*)&mb, (void*)&zmb, (void*)&hs, (void*)&out_mlgv
    };
    hipLaunchCooperativeKernel((const void*)k_seq, dim3(NWG), dim3(256),
                               args, 0, stream);

    hipLaunchKernelGGL(k_out, dim3(2000), dim3(256), 0, stream,
                       hs, out_w, out_b, outp);
}

// Round 5
// 1370.108 us; speedup vs baseline: 6.4416x; 1.5417x over previous
//
#include <hip/hip_runtime.h>
#include <hip/hip_bf16.h>

#define HD   1024
#define G4   4096
#define CND  64
#define LAT  256
#define VOC  32000
#define TT   256
#define ZCN  320    // LAT + CND
#define NWG  128
#define DEC0 301u   // decoder h version base (encoder uses 1..257)

typedef unsigned long long u64;
typedef __attribute__((ext_vector_type(8))) short short8;
typedef __attribute__((ext_vector_type(4))) float f32x4;

__device__ __forceinline__ float sigf(float x) { return 1.0f / (1.0f + expf(-x)); }

__device__ __forceinline__ u64 al64(const u64* p) {
    return __hip_atomic_load((u64*)p, __ATOMIC_RELAXED, __HIP_MEMORY_SCOPE_AGENT);
}
__device__ __forceinline__ void as64(u64* p, u64 v) {
    __hip_atomic_store(p, v, __ATOMIC_RELAXED, __HIP_MEMORY_SCOPE_AGENT);
}
__device__ __forceinline__ u64 packhv(float h, unsigned tag) {
    return ((u64)tag << 32) | (u64)__float_as_uint(h);
}

// ===========================================================================
// k_gemm3: C[m][n] = dot(Arow_m, B_n) + bias1[n] (+bias2[n])
// A fp32 (optional row-gather via ids), B fp32 [N][K] row-major, K=1024.
// On-the-fly 3xBF16 split: x = hi + lo;  A.B ~= AhBh + AhBl + AlBh
// (error ~2^-16 rel).  mfma_f32_16x16x32_bf16, 128x128 tile, BK=32,
// 4 waves x (4x4) 16x16 frags.  LDS tiles: ushort, row stride 40
// (banks: quad (5r+g)%8 -> conflict-free frag reads, 2-way on stores).
// ===========================================================================
#define BM  128
#define BN  128
#define BK  32
#define LDT 40

__device__ __forceinline__ void cvt2(float x, ushort& h, ushort& l)
{
    unsigned u = __float_as_uint(x);
    h = (ushort)(u >> 16);                       // truncate -> hi
    float hif = __uint_as_float(u & 0xffff0000u);
    l = (ushort)(__float_as_uint(x - hif) >> 16); // exact residual, trunc
}
__device__ __forceinline__ unsigned pk(ushort a, ushort b)
{
    return (unsigned)a | ((unsigned)b << 16);
}

__device__ __forceinline__ void stage16(const float* __restrict__ src,
                                        ushort* __restrict__ dh,
                                        ushort* __restrict__ dl)
{
    ushort h[16], l[16];
    #pragma unroll
    for (int i = 0; i < 16; i += 4) {
        float4 v = *(const float4*)(src + i);
        cvt2(v.x, h[i],   l[i]);
        cvt2(v.y, h[i+1], l[i+1]);
        cvt2(v.z, h[i+2], l[i+2]);
        cvt2(v.w, h[i+3], l[i+3]);
    }
    uint4 H0 = {pk(h[0],h[1]), pk(h[2],h[3]), pk(h[4],h[5]), pk(h[6],h[7])};
    uint4 H1 = {pk(h[8],h[9]), pk(h[10],h[11]), pk(h[12],h[13]), pk(h[14],h[15])};
    uint4 L0 = {pk(l[0],l[1]), pk(l[2],l[3]), pk(l[4],l[5]), pk(l[6],l[7])};
    uint4 L1 = {pk(l[8],l[9]), pk(l[10],l[11]), pk(l[12],l[13]), pk(l[14],l[15])};
    *(uint4*)(dh)     = H0;
    *(uint4*)(dh + 8) = H1;
    *(uint4*)(dl)     = L0;
    *(uint4*)(dl + 8) = L1;
}

__global__ __launch_bounds__(256) void k_gemm3(
    const float* __restrict__ A, const int* __restrict__ ids, int shift,
    const float* __restrict__ B, const float* __restrict__ bias1,
    const float* __restrict__ bias2, float* __restrict__ C,
    int ntn, int ldc)
{
    __shared__ ushort Ah[BM * LDT], Al[BM * LDT];
    __shared__ ushort Bh[BM * LDT], Bl[BM * LDT];

    const int bid  = blockIdx.x;
    const int m0   = (bid / ntn) * BM;
    const int n0   = (bid % ntn) * BN;
    const int tid  = threadIdx.x;
    const int lane = tid & 63;
    const int wid  = tid >> 6;
    const int wm   = (wid >> 1) * 64;
    const int wn   = (wid & 1) * 64;

    // staging: row sr = tid>>1 (0..127), 16-float half sc
    const int sr = tid >> 1;
    const int sc = (tid & 1) * 16;

    int ar = m0 + sr;
    if (ids) ar = shift ? ((ar == 0) ? 0 : ids[ar - 1]) : ids[ar];
    const float* arow = A + (size_t)ar * HD;
    const float* brow = B + (size_t)(n0 + sr) * HD;

    f32x4 acc[4][4] = {};

    const int fr = lane & 15;          // frag row/col within 16
    const int kg = (lane >> 4) * 8;    // k-offset within BK

    for (int k0 = 0; k0 < HD; k0 += BK) {
        __syncthreads();
        stage16(arow + k0 + sc, &Ah[sr * LDT + sc], &Al[sr * LDT + sc]);
        stage16(brow + k0 + sc, &Bh[sr * LDT + sc], &Bl[sr * LDT + sc]);
        __syncthreads();

        short8 fah[4], fal[4], fbh[4], fbl[4];
        #pragma unroll
        for (int f = 0; f < 4; ++f) {
            fah[f] = *(const short8*)&Ah[(wm + f * 16 + fr) * LDT + kg];
            fal[f] = *(const short8*)&Al[(wm + f * 16 + fr) * LDT + kg];
            fbh[f] = *(const short8*)&Bh[(wn + f * 16 + fr) * LDT + kg];
            fbl[f] = *(const short8*)&Bl[(wn + f * 16 + fr) * LDT + kg];
        }
        #pragma unroll
        for (int fi = 0; fi < 4; ++fi)
            #pragma unroll
            for (int fj = 0; fj < 4; ++fj) {
                acc[fi][fj] = __builtin_amdgcn_mfma_f32_16x16x32_bf16(
                                  fah[fi], fbh[fj], acc[fi][fj], 0, 0, 0);
                acc[fi][fj] = __builtin_amdgcn_mfma_f32_16x16x32_bf16(
                                  fah[fi], fbl[fj], acc[fi][fj], 0, 0, 0);
                acc[fi][fj] = __builtin_amdgcn_mfma_f32_16x16x32_bf16(
                                  fal[fi], fbh[fj], acc[fi][fj], 0, 0, 0);
            }
    }

    // D layout (m89-verified): col = lane&15, row = (lane>>4)*4 + reg
    const int rg = (lane >> 4) * 4;
    #pragma unroll
    for (int fj = 0; fj < 4; ++fj) {
        int col = n0 + wn + fj * 16 + fr;
        float bs = bias1[col];
        if (bias2) bs += bias2[col];
        #pragma unroll
        for (int fi = 0; fi < 4; ++fi) {
            #pragma unroll
            for (int r = 0; r < 4; ++r) {
                int rowi = m0 + wm + fi * 16 + rg + r;
                C[(size_t)rowi * ldc + col] = acc[fi][fj][r] + bs;
            }
        }
    }
}

// ===========================================================================
// k_seq: 128 WGs x 256 threads, fence-free tagged-mailbox dataflow.
// mb[slot][j] = {tag, fp32 h_j}, agent-scope 8B atomics in Infinity Cache.
// WG w owns rows [w*8, w*8+8).  whh slice in VGPRs (float4 wreg[32] =
// 128 regs/thread); h staged in LDS (broadcast-friendly, conflict-free).
// ===========================================================================
#define WCH 132    // LDS chunk stride (floats) for 128-float k-chunks

__device__ __forceinline__ void load_w(float4 (&wreg)[32],
                                       const float* __restrict__ w,
                                       int row, int s)
{
    const float4* p = (const float4*)(w + (size_t)row * HD + s * 128);
    #pragma unroll
    for (int u = 0; u < 32; ++u) wreg[u] = p[u];
}

// poll own 4 elements of version v, deposit into padded h_lds
__device__ __forceinline__ void read_h(const u64* mb, unsigned v,
                                       float* h_lds, int tid)
{
    const u64* p = mb + (size_t)(v & 1u) * HD + tid * 4;
    u64 e0, e1, e2, e3;
    for (;;) {
        e0 = al64(p); e1 = al64(p + 1); e2 = al64(p + 2); e3 = al64(p + 3);
        if ((unsigned)(e0 >> 32) >= v && (unsigned)(e1 >> 32) >= v &&
            (unsigned)(e2 >> 32) >= v && (unsigned)(e3 >> 32) >= v) break;
        __builtin_amdgcn_s_sleep(1);
    }
    float4 hv = make_float4(__uint_as_float((unsigned)e0),
                            __uint_as_float((unsigned)e1),
                            __uint_as_float((unsigned)e2),
                            __uint_as_float((unsigned)e3));
    *(float4*)&h_lds[(tid >> 5) * WCH + (tid & 31) * 4] = hv;
}

__device__ __forceinline__ void lstm_loop(
    const float* __restrict__ pre, u64* mb, float* __restrict__ hs,
    float& c_reg, const float4 (&wreg)[32], float* h_lds, float* g_lds,
    int tid, int s, int rl, int row, int j_own, unsigned vbase)
{
    for (int t = 0; t < TT; ++t) {
        unsigned v = vbase + (unsigned)t;
        float pv = 0.f;
        if (s == 0) pv = pre[(size_t)t * G4 + row];   // hides under poll

        read_h(mb, v, h_lds, tid);
        __syncthreads();

        const float4* h4 = (const float4*)h_lds;
        float a0 = 0.f, a1 = 0.f, a2 = 0.f, a3 = 0.f;
        #pragma unroll
        for (int u = 0; u < 32; ++u) {
            float4 wv = wreg[u];
            float4 hv = h4[s * 33 + u];   // 8 distinct addrs/wave -> broadcast
            a0 = fmaf(wv.x, hv.x, a0);
            a1 = fmaf(wv.y, hv.y, a1);
            a2 = fmaf(wv.z, hv.z, a2);
            a3 = fmaf(wv.w, hv.w, a3);
        }
        float acc = (a0 + a1) + (a2 + a3);
        acc += __shfl_xor(acc, 1);
        acc += __shfl_xor(acc, 2);
        acc += __shfl_xor(acc, 4);
        if (s == 0) g_lds[rl] = acc + pv;
        __syncthreads();

        if (tid < 8) {
            float xi = g_lds[tid],      xf = g_lds[8 + tid];
            float xg = g_lds[16 + tid], xo = g_lds[24 + tid];
            c_reg = sigf(xf) * c_reg + sigf(xi) * tanhf(xg);
            float hv = sigf(xo) * tanhf(c_reg);
            as64(&mb[(size_t)((v + 1u) & 1u) * HD + j_own], packhv(hv, v + 1u));
            if (hs) hs[(size_t)t * HD + j_own] = hv;
        }
    }
}

__global__ __launch_bounds__(256, 1) void k_seq(
    const float* __restrict__ cond_emb, const float* __restrict__ enc_whh,
    const float* __restrict__ mean_w, const float* __restrict__ mean_b,
    const float* __restrict__ lgv_w, const float* __restrict__ lgv_b,
    const float* __restrict__ l2h_w, const float* __restrict__ l2h_b,
    const float* __restrict__ l2c_w, const float* __restrict__ l2c_b,
    const float* __restrict__ dec_whh, const float* __restrict__ eps,
    const int* __restrict__ p_ic, const int* __restrict__ p_tc,
    const float* __restrict__ pre_enc, const float* __restrict__ pre_dec,
    u64* mb, u64* zmb,
    float* __restrict__ hs, float* __restrict__ out_mlgv)
{
    __shared__ float h_lds[8 * WCH];   // 4224 B
    __shared__ float g_lds[32];
    __shared__ float red[16];
    __shared__ float sm[4];

    const int w   = blockIdx.x;        // 0..127
    const int tid = threadIdx.x;
    const int s   = tid & 7;           // k-slice
    const int rl  = tid >> 3;          // 0..31
    const int gate = rl >> 3;
    const int jl   = rl & 7;
    const int row  = gate * HD + w * 8 + jl;
    const int j_own = w * 8 + tid;     // valid for tid<8
    float c_reg = 0.f;

    // ---- publish initial h (version 1): zeros(H-C) ++ cond_emb[input_c] ----
    if (tid < 8) {
        int j = j_own;
        float v0 = 0.f;
        int ic = p_ic[0];
        if (j >= HD - CND) v0 = cond_emb[ic * CND + (j - (HD - CND))];
        as64(&mb[(size_t)1 * HD + j], packhv(v0, 1u));
    }

    float4 wreg[32];
    load_w(wreg, enc_whh, row, s);
    lstm_loop(pre_enc, mb, nullptr, c_reg, wreg, h_lds, g_lds,
              tid, s, rl, row, j_own, 1u);

    // ---- latent 1: read hT (version 257), compute m, lgv, z ----
    read_h(mb, TT + 1u, h_lds, tid);
    __syncthreads();
    {
        int d = tid >> 6;              // 0..3
        int l64 = tid & 63;
        int l = w * 2 + (d & 1);
        const float* wrow = (d < 2 ? mean_w : lgv_w) + (size_t)l * HD;
        float acc = 0.f;
        #pragma unroll
        for (int e = 0; e < 16; ++e) {
            int k = e * 64 + l64;
            acc = fmaf(wrow[k], h_lds[(k >> 7) * WCH + (k & 127)], acc);
        }
        #pragma unroll
        for (int o = 32; o >= 1; o >>= 1) acc += __shfl_xor(acc, o);
        if (l64 == 0) sm[d] = acc + (d < 2 ? mean_b : lgv_b)[l];
    }
    __syncthreads();
    if (tid < 2) {
        int l = w * 2 + tid;
        float m = sm[tid], lg = sm[2 + tid];
        float z = eps[l] * expf(0.5f * lg) + m;
        as64(&zmb[l], packhv(z, 1u));
        out_mlgv[l]       = m;
        out_mlgv[LAT + l] = lg;
    }

    // ---- latent 2: poll z, build zc in LDS, compute dh0/dc0 ----
    {
        u64 e;
        const u64* p = zmb + tid;      // tid 0..255 covers all of z
        do { e = al64(p); } while ((unsigned)(e >> 32) < 1u);
        h_lds[tid] = __uint_as_float((unsigned)e);
    }
    if (tid < CND) {
        int tc = p_tc[0];
        h_lds[LAT + tid] = cond_emb[tc * CND + tid];
    }
    __syncthreads();
    {
        int r2 = tid >> 4;             // 0..15 (8 dh rows + 8 dc rows)
        int l16 = tid & 15;
        int which = r2 >> 3;
        int i = w * 8 + (r2 & 7);
        const float* wrow = (which ? l2c_w : l2h_w) + (size_t)i * ZCN;
        float acc = 0.f;
        #pragma unroll
        for (int e = 0; e < 20; ++e) {
            int k = e * 16 + l16;
            acc = fmaf(wrow[k], h_lds[k], acc);
        }
        acc += __shfl_xor(acc, 1);
        acc += __shfl_xor(acc, 2);
        acc += __shfl_xor(acc, 4);
        acc += __shfl_xor(acc, 8);
        if (l16 == 0) red[r2] = acc + (which ? l2c_b : l2h_b)[i];
    }
    __syncthreads();
    if (tid < 8) {
        // publish dh0 as version DEC0 (slot 1); safe: z handoff gates reuse
        as64(&mb[(size_t)(DEC0 & 1u) * HD + j_own], packhv(red[tid], DEC0));
        c_reg = red[8 + tid];          // dc0
    }

    load_w(wreg, dec_whh, row, s);
    lstm_loop(pre_dec, mb, hs, c_reg, wreg, h_lds, g_lds,
              tid, s, rl, row, j_own, DEC0);
}

// ---------------------------------------------------------------------------
extern "C" void kernel_launch(void* const* d_in, const int* in_sizes, int n_in,
                              void* d_out, int out_size, void* d_ws, size_t ws_size,
                              hipStream_t stream)
{
    const float* cond_emb = (const float*)d_in[0];
    const float* enc_emb  = (const float*)d_in[1];
    const float* enc_wih  = (const float*)d_in[2];
    const float* enc_whh  = (const float*)d_in[3];
    const float* enc_bih  = (const float*)d_in[4];
    const float* enc_bhh  = (const float*)d_in[5];
    const float* mean_w   = (const float*)d_in[6];
    const float* mean_b   = (const float*)d_in[7];
    const float* lgv_w    = (const float*)d_in[8];
    const float* lgv_b    = (const float*)d_in[9];
    const float* l2h_w    = (const float*)d_in[10];
    const float* l2h_b    = (const float*)d_in[11];
    const float* l2c_w    = (const float*)d_in[12];
    const float* l2c_b    = (const float*)d_in[13];
    const float* dec_emb  = (const float*)d_in[14];
    const float* dec_wih  = (const float*)d_in[15];
    const float* dec_whh  = (const float*)d_in[16];
    const float* dec_bih  = (const float*)d_in[17];
    const float* dec_bhh  = (const float*)d_in[18];
    const float* out_w    = (const float*)d_in[19];
    const float* out_b    = (const float*)d_in[20];
    const float* eps      = (const float*)d_in[21];
    const int* input_ids  = (const int*)d_in[22];
    const int* target_ids = (const int*)d_in[23];
    const int* p_ic       = (const int*)d_in[24];
    const int* p_tc       = (const int*)d_in[25];

    float* ws      = (float*)d_ws;
    float* pre_enc = ws;                        // 256*4096
    float* pre_dec = pre_enc + (size_t)TT * G4; // 256*4096
    float* hs      = pre_dec + (size_t)TT * G4; // 256*1024
    u64*   mb      = (u64*)(hs + (size_t)TT * HD);  // 2*1024 entries
    u64*   zmb     = mb + 2 * HD;               // 256 entries

    float* outp     = (float*)d_out;
    float* out_mlgv = outp + (size_t)TT * VOC;

    const int* no_ids = nullptr;
    const float* no_bias = nullptr;

    // reset mailbox tags (deterministic across graph replays)
    hipMemsetAsync(mb, 0, (2 * HD + LAT) * sizeof(u64), stream);

    // pre_enc / pre_dec: A = gathered emb rows, B = wih [4096][1024]
    {
        void* a0[] = {(void*)&enc_emb, (void*)&input_ids, (void*)&(int&)*(new int(0)),
                      (void*)&enc_wih, (void*)&enc_bih, (void*)&enc_bhh,
                      (void*)&pre_enc, (void*)&(int&)*(new int(32)), (void*)&(int&)*(new int(G4))};
        (void)a0; // (not used; direct launches below)
    }
    int shift0 = 0, shift1 = 1, ntn_pre = 32, ldc_pre = G4, ntn_out = 250, ldc_out = VOC;
    (void)shift0;

    hipLaunchKernelGGL(k_gemm3, dim3(2 * 32), dim3(256), 0, stream,
                       enc_emb, input_ids, 0, enc_wih, enc_bih, enc_bhh,
                       pre_enc, ntn_pre, ldc_pre);
    hipLaunchKernelGGL(k_gemm3, dim3(2 * 32), dim3(256), 0, stream,
                       dec_emb, target_ids, shift1, dec_wih, dec_bih, dec_bhh,
                       pre_dec, ntn_pre, ldc_pre);

    void* args[] = {
        (void*)&cond_emb, (void*)&enc_whh, (void*)&mean_w, (void*)&mean_b,
        (void*)&lgv_w, (void*)&lgv_b, (void*)&l2h_w, (void*)&l2h_b,
        (void*)&l2c_w, (void*)&l2c_b, (void*)&dec_whh, (void*)&eps,
        (void*)&p_ic, (void*)&p_tc, (void*)&pre_enc, (void*)&pre_dec,
        (void*)&mb, (void*)&zmb, (void*)&hs, (void*)&out_mlgv
    };
    hipLaunchCooperativeKernel((const void*)k_seq, dim3(NWG), dim3(256),
                               args, 0, stream);

    // logits: A = hs (no gather), B = out_w [32000][1024]
    hipLaunchKernelGGL(k_gemm3, dim3(2 * 250), dim3(256), 0, stream,
                       hs, no_ids, 0, out_w, out_b, no_bias,
                       outp, ntn_out, ldc_out);
}

// Round 6
// 1216.084 us; speedup vs baseline: 7.2574x; 1.1267x over previous
//
#include <hip/hip_runtime.h>
#include <hip/hip_bf16.h>

#define HD   1024
#define G4   4096
#define CND  64
#define LAT  256
#define VOC  32000
#define TT   256
#define ZCN  320    // LAT + CND
#define NWG  64
#define THR  512
#define DEC0 301u   // decoder h version base (encoder uses 1..257)

typedef unsigned long long u64;
typedef __attribute__((ext_vector_type(8))) short short8;
typedef __attribute__((ext_vector_type(4))) float f32x4;

__device__ __forceinline__ float sig_f(float x) {
    return 1.0f / (1.0f + __expf(-x));            // stable: x<<0 -> 0, x>>0 -> 1
}
__device__ __forceinline__ float tanh_f(float x) {
    float e = __expf(2.0f * x);                   // stable: inf -> 1, 0 -> -1
    return 1.0f - 2.0f / (e + 1.0f);
}

__device__ __forceinline__ u64 al64(const u64* p) {
    return __hip_atomic_load((u64*)p, __ATOMIC_RELAXED, __HIP_MEMORY_SCOPE_AGENT);
}
__device__ __forceinline__ void as64(u64* p, u64 v) {
    __hip_atomic_store(p, v, __ATOMIC_RELAXED, __HIP_MEMORY_SCOPE_AGENT);
}
__device__ __forceinline__ u64 packhv(float h, unsigned tag) {
    return ((u64)tag << 32) | (u64)__float_as_uint(h);
}

// ===========================================================================
// k_gemm3: C[m][n] = dot(Arow_m, B_n) + bias1[n] (+bias2[n])
// A fp32 (optional row-gather via ids), B fp32 [N][K] row-major, K=1024.
// On-the-fly 3xBF16 split: x = hi + lo;  A.B ~= AhBh + AhBl + AlBh.
// mfma_f32_16x16x32_bf16, 128x128 tile, BK=32, 4 waves x (4x4) frags.
// ===========================================================================
#define BM  128
#define BN  128
#define BK  32
#define LDT 40

__device__ __forceinline__ void cvt2(float x, ushort& h, ushort& l)
{
    unsigned u = __float_as_uint(x);
    h = (ushort)(u >> 16);
    float hif = __uint_as_float(u & 0xffff0000u);
    l = (ushort)(__float_as_uint(x - hif) >> 16);
}
__device__ __forceinline__ unsigned pk(ushort a, ushort b)
{
    return (unsigned)a | ((unsigned)b << 16);
}

__device__ __forceinline__ void stage16(const float* __restrict__ src,
                                        ushort* __restrict__ dh,
                                        ushort* __restrict__ dl)
{
    ushort h[16], l[16];
    #pragma unroll
    for (int i = 0; i < 16; i += 4) {
        float4 v = *(const float4*)(src + i);
        cvt2(v.x, h[i],   l[i]);
        cvt2(v.y, h[i+1], l[i+1]);
        cvt2(v.z, h[i+2], l[i+2]);
        cvt2(v.w, h[i+3], l[i+3]);
    }
    uint4 H0 = {pk(h[0],h[1]), pk(h[2],h[3]), pk(h[4],h[5]), pk(h[6],h[7])};
    uint4 H1 = {pk(h[8],h[9]), pk(h[10],h[11]), pk(h[12],h[13]), pk(h[14],h[15])};
    uint4 L0 = {pk(l[0],l[1]), pk(l[2],l[3]), pk(l[4],l[5]), pk(l[6],l[7])};
    uint4 L1 = {pk(l[8],l[9]), pk(l[10],l[11]), pk(l[12],l[13]), pk(l[14],l[15])};
    *(uint4*)(dh)     = H0;
    *(uint4*)(dh + 8) = H1;
    *(uint4*)(dl)     = L0;
    *(uint4*)(dl + 8) = L1;
}

__global__ __launch_bounds__(256) void k_gemm3(
    const float* __restrict__ A, const int* __restrict__ ids, int shift,
    const float* __restrict__ B, const float* __restrict__ bias1,
    const float* __restrict__ bias2, float* __restrict__ C,
    int ntn, int ldc)
{
    __shared__ ushort Ah[BM * LDT], Al[BM * LDT];
    __shared__ ushort Bh[BM * LDT], Bl[BM * LDT];

    const int bid  = blockIdx.x;
    const int m0   = (bid / ntn) * BM;
    const int n0   = (bid % ntn) * BN;
    const int tid  = threadIdx.x;
    const int lane = tid & 63;
    const int wid  = tid >> 6;
    const int wm   = (wid >> 1) * 64;
    const int wn   = (wid & 1) * 64;

    const int sr = tid >> 1;
    const int sc = (tid & 1) * 16;

    int ar = m0 + sr;
    if (ids) ar = shift ? ((ar == 0) ? 0 : ids[ar - 1]) : ids[ar];
    const float* arow = A + (size_t)ar * HD;
    const float* brow = B + (size_t)(n0 + sr) * HD;

    f32x4 acc[4][4] = {};

    const int fr = lane & 15;
    const int kg = (lane >> 4) * 8;

    for (int k0 = 0; k0 < HD; k0 += BK) {
        __syncthreads();
        stage16(arow + k0 + sc, &Ah[sr * LDT + sc], &Al[sr * LDT + sc]);
        stage16(brow + k0 + sc, &Bh[sr * LDT + sc], &Bl[sr * LDT + sc]);
        __syncthreads();

        short8 fah[4], fal[4], fbh[4], fbl[4];
        #pragma unroll
        for (int f = 0; f < 4; ++f) {
            fah[f] = *(const short8*)&Ah[(wm + f * 16 + fr) * LDT + kg];
            fal[f] = *(const short8*)&Al[(wm + f * 16 + fr) * LDT + kg];
            fbh[f] = *(const short8*)&Bh[(wn + f * 16 + fr) * LDT + kg];
            fbl[f] = *(const short8*)&Bl[(wn + f * 16 + fr) * LDT + kg];
        }
        #pragma unroll
        for (int fi = 0; fi < 4; ++fi)
            #pragma unroll
            for (int fj = 0; fj < 4; ++fj) {
                acc[fi][fj] = __builtin_amdgcn_mfma_f32_16x16x32_bf16(
                                  fah[fi], fbh[fj], acc[fi][fj], 0, 0, 0);
                acc[fi][fj] = __builtin_amdgcn_mfma_f32_16x16x32_bf16(
                                  fah[fi], fbl[fj], acc[fi][fj], 0, 0, 0);
                acc[fi][fj] = __builtin_amdgcn_mfma_f32_16x16x32_bf16(
                                  fal[fi], fbh[fj], acc[fi][fj], 0, 0, 0);
            }
    }

    const int rg = (lane >> 4) * 4;
    #pragma unroll
    for (int fj = 0; fj < 4; ++fj) {
        int col = n0 + wn + fj * 16 + fr;
        float bs = bias1[col];
        if (bias2) bs += bias2[col];
        #pragma unroll
        for (int fi = 0; fi < 4; ++fi) {
            #pragma unroll
            for (int r = 0; r < 4; ++r) {
                int rowi = m0 + wm + fi * 16 + rg + r;
                C[(size_t)rowi * ldc + col] = acc[fi][fj][r] + bs;
            }
        }
    }
}

// ===========================================================================
// k_seq: 64 WGs x 512 threads, fence-free tagged-mailbox dataflow.
// mb[slot][j] = {tag, fp32 h_j}, agent-scope 8B atomics in Infinity Cache.
// WG w owns rows [w*16, w*16+16).  rl = tid>>3 in 0..63: gate = rl>>4,
// jl = rl&15, row = gate*HD + w*16 + jl; s = tid&7 = 128-float k-slice
// held in VGPRs/AGPRs.  pre[t+1] prefetched one step ahead (HBM latency
// off the critical path).  Gate activations parallelized over 64 lanes.
// ===========================================================================
#define WCH 132    // LDS chunk stride (floats) for 128-float k-chunks

__device__ __forceinline__ void load_w(float4 (&wreg)[32],
                                       const float* __restrict__ w,
                                       int row, int s)
{
    const float4* p = (const float4*)(w + (size_t)row * HD + s * 128);
    #pragma unroll
    for (int u = 0; u < 32; ++u) wreg[u] = p[u];
}

// poll own 2 entries of version v, deposit into padded h_lds
__device__ __forceinline__ void read_h(const u64* mb, unsigned v,
                                       float* h_lds, int tid)
{
    const u64* p = mb + (size_t)(v & 1u) * HD + tid * 2;
    u64 e0, e1;
    for (;;) {
        e0 = al64(p); e1 = al64(p + 1);
        if ((unsigned)(e0 >> 32) >= v && (unsigned)(e1 >> 32) >= v) break;
        __builtin_amdgcn_s_sleep(1);
    }
    int j = tid * 2;
    *(float2*)&h_lds[(j >> 7) * WCH + (j & 127)] =
        make_float2(__uint_as_float((unsigned)e0),
                    __uint_as_float((unsigned)e1));
}

__device__ __forceinline__ void lstm_loop(
    const float* __restrict__ pre, u64* mb, float* __restrict__ hs,
    float& c_reg, const float4 (&wreg)[32], float* h_lds, float* g_lds,
    int tid, int s, int rl, int row, int j_own, unsigned vbase)
{
    float pv = (s == 0) ? pre[row] : 0.f;          // t=0, ahead of the loop
    for (int t = 0; t < TT; ++t) {
        unsigned v = vbase + (unsigned)t;
        // prefetch next step's pre: HBM latency hides under poll + compute
        float pv_nxt = 0.f;
        if (s == 0 && t + 1 < TT) pv_nxt = pre[(size_t)(t + 1) * G4 + row];

        read_h(mb, v, h_lds, tid);
        __syncthreads();

        const float4* h4 = (const float4*)h_lds;
        float a0 = 0.f, a1 = 0.f, a2 = 0.f, a3 = 0.f;
        #pragma unroll
        for (int u = 0; u < 32; ++u) {
            float4 wv = wreg[u];
            float4 hv = h4[s * 33 + u];    // 8 distinct addrs/wave: broadcast
            a0 = fmaf(wv.x, hv.x, a0);
            a1 = fmaf(wv.y, hv.y, a1);
            a2 = fmaf(wv.z, hv.z, a2);
            a3 = fmaf(wv.w, hv.w, a3);
        }
        float acc = (a0 + a1) + (a2 + a3);
        acc += __shfl_xor(acc, 1);
        acc += __shfl_xor(acc, 2);
        acc += __shfl_xor(acc, 4);
        if (s == 0) g_lds[rl] = acc + pv;
        __syncthreads();

        if (tid < 64) {
            // lanes 0-15: i, 16-31: f, 32-47: g(tanh), 48-63: o
            float g = g_lds[tid];
            float a = (tid >= 32 && tid < 48) ? tanh_f(g) : sig_f(g);
            float xf = __shfl(a, tid + 16);
            float xg = __shfl(a, tid + 32);
            float xo = __shfl(a, tid + 48);
            if (tid < 16) {
                c_reg = xf * c_reg + a * xg;
                float hv = xo * tanh_f(c_reg);
                as64(&mb[(size_t)((v + 1u) & 1u) * HD + j_own],
                     packhv(hv, v + 1u));
                if (hs) hs[(size_t)t * HD + j_own] = hv;
            }
        }
        pv = pv_nxt;
    }
}

__global__ __launch_bounds__(512, 1) void k_seq(
    const float* __restrict__ cond_emb, const float* __restrict__ enc_whh,
    const float* __restrict__ mean_w, const float* __restrict__ mean_b,
    const float* __restrict__ lgv_w, const float* __restrict__ lgv_b,
    const float* __restrict__ l2h_w, const float* __restrict__ l2h_b,
    const float* __restrict__ l2c_w, const float* __restrict__ l2c_b,
    const float* __restrict__ dec_whh, const float* __restrict__ eps,
    const int* __restrict__ p_ic, const int* __restrict__ p_tc,
    const float* __restrict__ pre_enc, const float* __restrict__ pre_dec,
    u64* mb, u64* zmb,
    float* __restrict__ hs, float* __restrict__ out_mlgv)
{
    __shared__ float h_lds[8 * WCH];   // 4224 B
    __shared__ float g_lds[64];
    __shared__ float red[32];
    __shared__ float sm[8];

    const int w   = blockIdx.x;        // 0..63
    const int tid = threadIdx.x;       // 0..511
    const int s   = tid & 7;           // k-slice
    const int rl  = tid >> 3;          // 0..63
    const int gate = rl >> 4;
    const int jl   = rl & 15;
    const int row  = gate * HD + w * 16 + jl;
    const int j_own = w * 16 + tid;    // valid for tid<16
    float c_reg = 0.f;

    // ---- publish initial h (version 1): zeros(H-C) ++ cond_emb[input_c] ----
    if (tid < 16) {
        int j = j_own;
        float v0 = 0.f;
        int ic = p_ic[0];
        if (j >= HD - CND) v0 = cond_emb[ic * CND + (j - (HD - CND))];
        as64(&mb[(size_t)1 * HD + j], packhv(v0, 1u));
    }

    float4 wreg[32];
    load_w(wreg, enc_whh, row, s);
    lstm_loop(pre_enc, mb, nullptr, c_reg, wreg, h_lds, g_lds,
              tid, s, rl, row, j_own, 1u);

    // ---- latent 1: read hT (version 257), compute m, lgv, z ----
    read_h(mb, TT + 1u, h_lds, tid);
    __syncthreads();
    {
        int d = tid >> 6;              // 0..7 (waves); <4: mean, >=4: lgv
        int l64 = tid & 63;
        int l = w * 4 + (d & 3);
        const float* wrow = (d < 4 ? mean_w : lgv_w) + (size_t)l * HD;
        float acc = 0.f;
        #pragma unroll
        for (int e = 0; e < 16; ++e) {
            int k = e * 64 + l64;
            acc = fmaf(wrow[k], h_lds[(k >> 7) * WCH + (k & 127)], acc);
        }
        #pragma unroll
        for (int o = 32; o >= 1; o >>= 1) acc += __shfl_xor(acc, o);
        if (l64 == 0) sm[d] = acc + (d < 4 ? mean_b : lgv_b)[l];
    }
    __syncthreads();
    if (tid < 4) {
        int l = w * 4 + tid;
        float m = sm[tid], lg = sm[4 + tid];
        float z = eps[l] * __expf(0.5f * lg) + m;
        as64(&zmb[l], packhv(z, 1u));
        out_mlgv[l]       = m;
        out_mlgv[LAT + l] = lg;
    }

    // ---- latent 2: poll z, build zc in LDS, compute dh0/dc0 ----
    if (tid < LAT) {
        u64 e;
        const u64* p = zmb + tid;
        do { e = al64(p); } while ((unsigned)(e >> 32) < 1u);
        h_lds[tid] = __uint_as_float((unsigned)e);
    } else if (tid < ZCN) {
        int tc = p_tc[0];
        h_lds[tid] = cond_emb[tc * CND + (tid - LAT)];
    }
    __syncthreads();
    {
        int r2 = tid >> 4;             // 0..31 (16 dh rows + 16 dc rows)
        int l16 = tid & 15;
        int which = r2 >> 4;           // 0: l2h, 1: l2c
        int i = w * 16 + (r2 & 15);
        const float* wrow = (which ? l2c_w : l2h_w) + (size_t)i * ZCN;
        float acc = 0.f;
        #pragma unroll
        for (int e = 0; e < 20; ++e) {
            int k = e * 16 + l16;
            acc = fmaf(wrow[k], h_lds[k], acc);
        }
        acc += __shfl_xor(acc, 1);
        acc += __shfl_xor(acc, 2);
        acc += __shfl_xor(acc, 4);
        acc += __shfl_xor(acc, 8);
        if (l16 == 0) red[r2] = acc + (which ? l2c_b : l2h_b)[i];
    }
    __syncthreads();
    if (tid < 16) {
        // publish dh0 (version DEC0, slot 1); z handoff gates slot reuse
        as64(&mb[(size_t)(DEC0 & 1u) * HD + j_own], packhv(red[tid], DEC0));
        c_reg = red[16 + tid];         // dc0
    }

    load_w(wreg, dec_whh, row, s);
    lstm_loop(pre_dec, mb, hs, c_reg, wreg, h_lds, g_lds,
              tid, s, rl, row, j_own, DEC0);
}

// ---------------------------------------------------------------------------
extern "C" void kernel_launch(void* const* d_in, const int* in_sizes, int n_in,
                              void* d_out, int out_size, void* d_ws, size_t ws_size,
                              hipStream_t stream)
{
    const float* cond_emb = (const float*)d_in[0];
    const float* enc_emb  = (const float*)d_in[1];
    const float* enc_wih  = (const float*)d_in[2];
    const float* enc_whh  = (const float*)d_in[3];
    const float* enc_bih  = (const float*)d_in[4];
    const float* enc_bhh  = (const float*)d_in[5];
    const float* mean_w   = (const float*)d_in[6];
    const float* mean_b   = (const float*)d_in[7];
    const float* lgv_w    = (const float*)d_in[8];
    const float* lgv_b    = (const float*)d_in[9];
    const float* l2h_w    = (const float*)d_in[10];
    const float* l2h_b    = (const float*)d_in[11];
    const float* l2c_w    = (const float*)d_in[12];
    const float* l2c_b    = (const float*)d_in[13];
    const float* dec_emb  = (const float*)d_in[14];
    const float* dec_wih  = (const float*)d_in[15];
    const float* dec_whh  = (const float*)d_in[16];
    const float* dec_bih  = (const float*)d_in[17];
    const float* dec_bhh  = (const float*)d_in[18];
    const float* out_w    = (const float*)d_in[19];
    const float* out_b    = (const float*)d_in[20];
    const float* eps      = (const float*)d_in[21];
    const int* input_ids  = (const int*)d_in[22];
    const int* target_ids = (const int*)d_in[23];
    const int* p_ic       = (const int*)d_in[24];
    const int* p_tc       = (const int*)d_in[25];

    float* ws      = (float*)d_ws;
    float* pre_enc = ws;                        // 256*4096
    float* pre_dec = pre_enc + (size_t)TT * G4; // 256*4096
    float* hs      = pre_dec + (size_t)TT * G4; // 256*1024
    u64*   mb      = (u64*)(hs + (size_t)TT * HD);  // 2*1024 entries
    u64*   zmb     = mb + 2 * HD;               // 256 entries

    float* outp     = (float*)d_out;
    float* out_mlgv = outp + (size_t)TT * VOC;

    const int* no_ids = nullptr;
    const float* no_bias = nullptr;

    // reset mailbox tags (deterministic across graph replays)
    hipMemsetAsync(mb, 0, (2 * HD + LAT) * sizeof(u64), stream);

    hipLaunchKernelGGL(k_gemm3, dim3(2 * 32), dim3(256), 0, stream,
                       enc_emb, input_ids, 0, enc_wih, enc_bih, enc_bhh,
                       pre_enc, 32, G4);
    hipLaunchKernelGGL(k_gemm3, dim3(2 * 32), dim3(256), 0, stream,
                       dec_emb, target_ids, 1, dec_wih, dec_bih, dec_bhh,
                       pre_dec, 32, G4);

    void* args[] = {
        (void*)&cond_emb, (void*)&enc_whh, (void*)&mean_w, (void*)&mean_b,
        (void*)&lgv_w, (void*)&lgv_b, (void*)&l2h_w, (void*)&l2h_b,
        (void*)&l2c_w, (void*)&l2c_b, (void*)&dec_whh, (void*)&eps,
        (void*)&p_ic, (void*)&p_tc, (void*)&pre_enc, (void*)&pre_dec,
        (void*)&mb, (void*)&zmb, (void*)&hs, (void*)&out_mlgv
    };
    hipLaunchCooperativeKernel((const void*)k_seq, dim3(NWG), dim3(THR),
                               args, 0, stream);

    hipLaunchKernelGGL(k_gemm3, dim3(2 * 250), dim3(256), 0, stream,
                       hs, no_ids, 0, out_w, out_b, no_bias,
                       outp, 250, VOC);
}